// Round 7
// baseline (85.846 us; speedup 1.0000x reference)
//
#include <hip/hip_runtime.h>

typedef unsigned short u16;
typedef unsigned int u32;
typedef float f32x4 __attribute__((ext_vector_type(4)));
typedef short s16x8 __attribute__((ext_vector_type(8)));
typedef unsigned int u32x2 __attribute__((ext_vector_type(2)));

#define NB 4
#define NT 4096
#define ND 128
#define NQ (NB * NT)

// (1/sqrt(128)) * log2(e)  -- folded into Q so softmax runs in exp2 domain
#define QK_SCALE 0.12751879523138906f

using as3_void = __attribute__((address_space(3))) void;
using as1_void = __attribute__((address_space(1))) void;

__device__ __forceinline__ u16 f2bf(float x){
  unsigned u = __float_as_uint(x);
  return (u16)((u + 0x7FFFu + ((u >> 16) & 1u)) >> 16);   // RNE
}
__device__ __forceinline__ u32 cvtpk(float lo, float hi){
  u32 r; asm("v_cvt_pk_bf16_f32 %0, %1, %2" : "=v"(r) : "v"(lo), "v"(hi)); return r;
}
__device__ __forceinline__ f32x4 mfma16(s16x8 a, s16x8 b, f32x4 c){
  return __builtin_amdgcn_mfma_f32_16x16x32_bf16(a, b, c, 0, 0, 0);
}

// ---------------- kernel 0: weights -> bf16, transposed wt[mat][f][c] ----------------
__global__ void k_wprep(const float* __restrict__ Wq, const float* __restrict__ Wk,
                        const float* __restrict__ Wv, u16* __restrict__ WT){
  int mat = blockIdx.x >> 7;
  int f   = blockIdx.x & 127;
  const float* W = (mat == 0) ? Wq : (mat == 1) ? Wk : Wv;
  int c = threadIdx.x;
  WT[mat * 16384 + f * 128 + c] = f2bf(W[c * 128 + f]);
}

// ---------------- kernel 1: QKV projection (R2-verified layouts) ----------------
// Qs : bf16 [NQ][128], scaled by QK_SCALE (row-major)
// Ks : bf16 [NQ][128], element (r,f) at col f ^ ((r&7)<<3)       (b128-read swizzle)
// VTs: bf16 [B][128][N], element (f,n) at col n ^ ((f&3)<<3)     (within-32 swizzle)
__global__ __launch_bounds__(256) void k_proj(
    const float* __restrict__ X, const u16* __restrict__ WT,
    const float* __restrict__ bq, const float* __restrict__ bk, const float* __restrict__ bv,
    u16* __restrict__ Qs, u16* __restrict__ Ks, u16* __restrict__ VTs)
{
  const int lane = threadIdx.x & 63;
  const int w    = threadIdx.x >> 6;
  const int lm = lane & 15, lg = lane >> 4;
  const int rowbase = blockIdx.x * 64 + w * 16;

  s16x8 a[4];
  const float* xr = X + (rowbase + lm) * ND;
  #pragma unroll
  for (int kc = 0; kc < 4; ++kc){
    f32x4 x0 = *(const f32x4*)(xr + kc * 32 + lg * 8);
    f32x4 x1 = *(const f32x4*)(xr + kc * 32 + lg * 8 + 4);
    s16x8 t;
    t[0]=(short)f2bf(x0[0]); t[1]=(short)f2bf(x0[1]); t[2]=(short)f2bf(x0[2]); t[3]=(short)f2bf(x0[3]);
    t[4]=(short)f2bf(x1[0]); t[5]=(short)f2bf(x1[1]); t[6]=(short)f2bf(x1[2]); t[7]=(short)f2bf(x1[3]);
    a[kc] = t;
  }

  #pragma unroll
  for (int mat = 0; mat < 3; ++mat){
    const float* bias = (mat==0) ? bq : (mat==1) ? bk : bv;
    float bl[8];
    #pragma unroll
    for (int n = 0; n < 8; ++n) bl[n] = bias[n * 16 + lm];
    f32x4 acc[8];
    #pragma unroll
    for (int n = 0; n < 8; ++n) acc[n] = f32x4{0.f,0.f,0.f,0.f};
    #pragma unroll
    for (int kc = 0; kc < 4; ++kc){
      #pragma unroll
      for (int n = 0; n < 8; ++n){
        s16x8 bf = *(const s16x8*)&WT[mat*16384 + (n*16 + lm)*128 + kc*32 + lg*8];
        acc[n] = mfma16(a[kc], bf, acc[n]);
      }
    }
    #pragma unroll
    for (int n = 0; n < 8; ++n){
      int f = n * 16 + lm;
      #pragma unroll
      for (int i = 0; i < 4; ++i){
        int r = rowbase + lg * 4 + i;
        float val = acc[n][i] + bl[n];
        if (mat == 0){
          Qs[r * ND + f] = f2bf(val * QK_SCALE);
        } else if (mat == 1){
          Ks[r * ND + (f ^ ((r & 7) << 3))] = f2bf(val);
        } else {
          int bb = r >> 12, nt = r & (NT - 1);
          VTs[(bb * ND + f) * NT + (nt ^ ((f & 3) << 3))] = f2bf(val);
        }
      }
    }
  }
}

// ---------------- kernel 2: flash attention, 16x16 MFMA, swapped QK^T ----------
// grid 256 = 4 batches x 64 q-blocks(64 q). 8 waves = 2 q-waves(32 q) x 4 kv-groups
// (1024 kv each, 32 tiles of 32). S^T = mfma16(K, Q): lane holds 4 contiguous kv per
// q=lm -> P write is one b64 per (sq,n). pbuf[q][kv ^ ((q&3)<<3)]; pa = b128 row read.
__global__ __launch_bounds__(512, 2) void k_attn(
    const u16* __restrict__ Qs, const u16* __restrict__ Ks,
    const u16* __restrict__ VTs, float* __restrict__ Out)
{
  __shared__ __align__(16) u16 lds[73728];          // 144 KiB
  u16* kbuf = lds;                                  // [2][4][32*128]
  u16* vbuf = lds + 32768;                          // [2][4][128*32]
  u16* pbuf = lds + 65536;                          // [8][32*32]

  // XCD-chunked: xcd = lin&7 -> batch b = xcd>>1; 2 XCDs per batch (K/V fit in L2)
  const int lin = blockIdx.x;
  const int b   = (lin & 7) >> 1;
  const int qb  = (lin >> 3) + ((lin & 1) << 5);    // 0..63

  const int lane = threadIdx.x & 63;
  const int w  = threadIdx.x >> 6;
  const int g  = w >> 1, qw = w & 1;                // kv-group, q-wave
  const int lm = lane & 15, lg = lane >> 4;
  const int q0 = b * NT + qb * 64 + qw * 32;        // global q base for this wave

  // Q frags in registers: rows q0 + sq*16 + lm, k = kc*32 + lg*8 + j  (R2 map)
  s16x8 aq[2][4];
  #pragma unroll
  for (int sq = 0; sq < 2; ++sq){
    const u16* qr = Qs + (size_t)(q0 + sq * 16 + lm) * ND;
    #pragma unroll
    for (int kc = 0; kc < 4; ++kc) aq[sq][kc] = *(const s16x8*)(qr + kc * 32 + lg * 8);
  }

  f32x4 o[2][8];
  #pragma unroll
  for (int sq = 0; sq < 2; ++sq)
    #pragma unroll
    for (int n = 0; n < 8; ++n) o[sq][n] = f32x4{0.f,0.f,0.f,0.f};
  float l_[2] = {0.f, 0.f};

  // staging pointers (group g covers kv [g*1024, g*1024+1024), tiles of 32)
  const u16* gk = Ks  + ((size_t)b * NT + g * 1024 + qw * 16 + (lane >> 4)) * ND + (lane & 15) * 8;
  const u16* gv = VTs + ((size_t)b * ND + qw * 64 + (lane >> 2)) * NT + g * 1024 + (lane & 3) * 8;

  auto stage = [&](int par){
    u16* kd = kbuf + par * 16384 + g * 4096 + qw * 2048;
    u16* vd = vbuf + par * 16384 + g * 4096 + qw * 2048;
    #pragma unroll
    for (int j = 0; j < 4; ++j){
      __builtin_amdgcn_global_load_lds((const as1_void*)(gk + (size_t)j * 4 * ND),
                                       (as3_void*)(kd + j * 512), 16, 0, 0);
      __builtin_amdgcn_global_load_lds((const as1_void*)(gv + (size_t)j * 16 * NT),
                                       (as3_void*)(vd + j * 512), 16, 0, 0);
    }
    gk += (size_t)32 * ND;
    gv += 32;
  };

  stage(0);
  __syncthreads();
  int par = 0;

  const int pw = w * 1024;                      // this wave's pbuf base
  const int kswz = (lm & 7) << 3;               // K b128-read swizzle (row&7 == lm&7)
  const int vswz = (lm & 3) << 3;               // V b128-read swizzle (row&3 == lm&3)
  const int pswz = (lm & 3) << 3;               // P swizzle: memcol = kv ^ ((q&3)<<3)

  for (int t = 0; t < 32; ++t){
    if (t < 31) stage(par ^ 1);                 // prefetch next tile
    const u16* kb = kbuf + par * 16384 + g * 4096;
    const u16* vb = vbuf + par * 16384 + g * 4096;

    // ---- S^T = K Q : swapped operands; kf shared across sq ----
    f32x4 st[2][2];
    #pragma unroll
    for (int sq = 0; sq < 2; ++sq)
      #pragma unroll
      for (int n = 0; n < 2; ++n) st[sq][n] = f32x4{0.f,0.f,0.f,0.f};
    __builtin_amdgcn_s_setprio(1);
    #pragma unroll
    for (int kc = 0; kc < 4; ++kc){
      #pragma unroll
      for (int n = 0; n < 2; ++n){
        s16x8 kf = *(const s16x8*)&kb[(n * 16 + lm) * 128 + ((kc * 32 + lg * 8) ^ kswz)];
        st[0][n] = mfma16(kf, aq[0][kc], st[0][n]);
        st[1][n] = mfma16(kf, aq[1][kc], st[1][n]);
      }
    }
    __builtin_amdgcn_s_setprio(0);

    // ---- fixed-ref softmax; lane holds kv = n*16 + lg*4 + i for q = sq*16+lm ----
    #pragma unroll
    for (int sq = 0; sq < 2; ++sq){
      #pragma unroll
      for (int n = 0; n < 2; ++n){
        float p0 = __builtin_amdgcn_exp2f(st[sq][n][0]);
        float p1 = __builtin_amdgcn_exp2f(st[sq][n][1]);
        float p2 = __builtin_amdgcn_exp2f(st[sq][n][2]);
        float p3 = __builtin_amdgcn_exp2f(st[sq][n][3]);
        l_[sq] += (p0 + p1) + (p2 + p3);
        *(u32x2*)&pbuf[pw + (sq * 16 + lm) * 32 + ((n * 16 + lg * 4) ^ pswz)] =
            u32x2{cvtpk(p0, p1), cvtpk(p2, p3)};
      }
    }
    asm volatile("s_waitcnt lgkmcnt(0)" ::: "memory");

    // ---- O += P V : pa b128 row read (same swizzle); vf shared across sq ----
    s16x8 pa[2];
    #pragma unroll
    for (int sq = 0; sq < 2; ++sq)
      pa[sq] = *(const s16x8*)&pbuf[pw + (sq * 16 + lm) * 32 + ((lg * 8) ^ pswz)];
    __builtin_amdgcn_s_setprio(1);
    #pragma unroll
    for (int nf = 0; nf < 8; ++nf){
      s16x8 vf = *(const s16x8*)&vb[(nf * 16 + lm) * 32 + ((lg * 8) ^ vswz)];
      o[0][nf] = mfma16(pa[0], vf, o[0][nf]);
      o[1][nf] = mfma16(pa[1], vf, o[1][nf]);
    }
    __builtin_amdgcn_s_setprio(0);

    __syncthreads();   // drains prefetch vmcnt + releases buf[par]
    par ^= 1;
  }

  // ---- epilogue: reduce l over lg; merge 4 kv-groups in LDS; write Out ----
  #pragma unroll
  for (int sq = 0; sq < 2; ++sq){
    float v = l_[sq];
    v += __shfl_xor(v, 16);
    v += __shfl_xor(v, 32);
    l_[sq] = v;                       // all lanes: l for q = sq*16+lm
  }

  float* mbF = (float*)lds;            // [3][64][128] f32 partial O (96 KiB)
  float* lF  = (float*)lds + 24576;    // [4][64] f32 partial l (1 KiB)
  if (lg == 0){
    lF[g * 64 + qw * 32 + lm]      = l_[0];
    lF[g * 64 + qw * 32 + 16 + lm] = l_[1];
  }
  if (g){
    #pragma unroll
    for (int sq = 0; sq < 2; ++sq){
      #pragma unroll
      for (int i = 0; i < 4; ++i){
        const int row = (g - 1) * 64 + qw * 32 + sq * 16 + lg * 4 + i;
        #pragma unroll
        for (int nf = 0; nf < 8; ++nf)
          mbF[row * 128 + nf * 16 + lm] = o[sq][nf][i];
      }
    }
  }
  __syncthreads();
  if (!g){
    #pragma unroll
    for (int sq = 0; sq < 2; ++sq){
      #pragma unroll
      for (int i = 0; i < 4; ++i){
        const int rloc = qw * 32 + sq * 16 + lg * 4 + i;
        const float inv = 1.f / (lF[rloc] + lF[64 + rloc] + lF[128 + rloc] + lF[192 + rloc]);
        const size_t r = (size_t)(q0 + sq * 16 + lg * 4 + i);
        #pragma unroll
        for (int nf = 0; nf < 8; ++nf){
          const int f = nf * 16 + lm;
          float val = o[sq][nf][i] + mbF[rloc * 128 + f]
                    + mbF[(64 + rloc) * 128 + f] + mbF[(128 + rloc) * 128 + f];
          Out[r * ND + f] = val * inv;
        }
      }
    }
  }
}

extern "C" void kernel_launch(void* const* d_in, const int* in_sizes, int n_in,
                              void* d_out, int out_size, void* d_ws, size_t ws_size,
                              hipStream_t stream) {
  const float* X  = (const float*)d_in[0];
  const float* Wq = (const float*)d_in[1];
  const float* bq = (const float*)d_in[2];
  const float* Wk = (const float*)d_in[3];
  const float* bk = (const float*)d_in[4];
  const float* Wv = (const float*)d_in[5];
  const float* bv = (const float*)d_in[6];
  float* Out = (float*)d_out;

  u16* Qs  = (u16*)d_ws;                        // 4 MiB
  u16* Ks  = Qs  + (size_t)NQ * ND;             // 4 MiB
  u16* VTs = Ks  + (size_t)NQ * ND;             // 4 MiB
  u16* WT  = VTs + (size_t)NQ * ND;             // 96 KiB

  hipLaunchKernelGGL(k_wprep, dim3(3 * 128), dim3(128), 0, stream, Wq, Wk, Wv, WT);
  hipLaunchKernelGGL(k_proj,  dim3(NQ / 64), dim3(256), 0, stream,
                     X, WT, bq, bk, bv, Qs, Ks, VTs);
  hipLaunchKernelGGL(k_attn,  dim3(256), dim3(512), 0, stream, Qs, Ks, VTs, Out);
}

// Round 8
// 79.236 us; speedup vs baseline: 1.0834x; 1.0834x over previous
//
#include <hip/hip_runtime.h>

typedef unsigned short u16;
typedef unsigned int u32;
typedef float f32x4 __attribute__((ext_vector_type(4)));
typedef short s16x8 __attribute__((ext_vector_type(8)));
typedef unsigned int u32x2 __attribute__((ext_vector_type(2)));
typedef unsigned int u32x4 __attribute__((ext_vector_type(4)));

#define NB 4
#define NT 4096
#define ND 128
#define NQ (NB * NT)

// (1/sqrt(128)) * log2(e)  -- folded into Q so softmax runs in exp2 domain
#define QK_SCALE 0.12751879523138906f

using as3_void = __attribute__((address_space(3))) void;
using as1_void = __attribute__((address_space(1))) void;

__device__ __forceinline__ u16 f2bf(float x){
  unsigned u = __float_as_uint(x);
  return (u16)((u + 0x7FFFu + ((u >> 16) & 1u)) >> 16);   // RNE
}
__device__ __forceinline__ u32 cvtpk(float lo, float hi){
  u32 r; asm("v_cvt_pk_bf16_f32 %0, %1, %2" : "=v"(r) : "v"(lo), "v"(hi)); return r;
}
__device__ __forceinline__ f32x4 mfma16(s16x8 a, s16x8 b, f32x4 c){
  return __builtin_amdgcn_mfma_f32_16x16x32_bf16(a, b, c, 0, 0, 0);
}

// ---------------- kernel 0: weights -> bf16, transposed wt[mat][f][c] ----------------
__global__ void k_wprep(const float* __restrict__ Wq, const float* __restrict__ Wk,
                        const float* __restrict__ Wv, u16* __restrict__ WT){
  int mat = blockIdx.x >> 7;
  int f   = blockIdx.x & 127;
  const float* W = (mat == 0) ? Wq : (mat == 1) ? Wk : Wv;
  int c = threadIdx.x;
  WT[mat * 16384 + f * 128 + c] = f2bf(W[c * 128 + f]);
}

// ---------------- kernel 1: QKV projection ----------------
// Qs : bf16 [NQ][128], scaled by QK_SCALE (row-major)
// Ks : bf16 [NQ][128], element (r,f) at col f ^ ((r&7)<<3)                 (b128-read swizzle)
// VTs: bf16 [B][128][N], (f,n) at col n ^ ((f&3)<<3) ^ (((f>>2)&1)<<2)     (b64-read swizzle)
__global__ __launch_bounds__(256) void k_proj(
    const float* __restrict__ X, const u16* __restrict__ WT,
    const float* __restrict__ bq, const float* __restrict__ bk, const float* __restrict__ bv,
    u16* __restrict__ Qs, u16* __restrict__ Ks, u16* __restrict__ VTs)
{
  const int lane = threadIdx.x & 63;
  const int w    = threadIdx.x >> 6;
  const int lm = lane & 15, lg = lane >> 4;
  const int rowbase = blockIdx.x * 64 + w * 16;

  s16x8 a[4];
  const float* xr = X + (rowbase + lm) * ND;
  #pragma unroll
  for (int kc = 0; kc < 4; ++kc){
    f32x4 x0 = *(const f32x4*)(xr + kc * 32 + lg * 8);
    f32x4 x1 = *(const f32x4*)(xr + kc * 32 + lg * 8 + 4);
    s16x8 t;
    t[0]=(short)f2bf(x0[0]); t[1]=(short)f2bf(x0[1]); t[2]=(short)f2bf(x0[2]); t[3]=(short)f2bf(x0[3]);
    t[4]=(short)f2bf(x1[0]); t[5]=(short)f2bf(x1[1]); t[6]=(short)f2bf(x1[2]); t[7]=(short)f2bf(x1[3]);
    a[kc] = t;
  }

  #pragma unroll
  for (int mat = 0; mat < 3; ++mat){
    const float* bias = (mat==0) ? bq : (mat==1) ? bk : bv;
    float bl[8];
    #pragma unroll
    for (int n = 0; n < 8; ++n) bl[n] = bias[n * 16 + lm];
    f32x4 acc[8];
    #pragma unroll
    for (int n = 0; n < 8; ++n) acc[n] = f32x4{0.f,0.f,0.f,0.f};
    #pragma unroll
    for (int kc = 0; kc < 4; ++kc){
      #pragma unroll
      for (int n = 0; n < 8; ++n){
        s16x8 bf = *(const s16x8*)&WT[mat*16384 + (n*16 + lm)*128 + kc*32 + lg*8];
        acc[n] = mfma16(a[kc], bf, acc[n]);
      }
    }
    #pragma unroll
    for (int n = 0; n < 8; ++n){
      int f = n * 16 + lm;
      #pragma unroll
      for (int i = 0; i < 4; ++i){
        int r = rowbase + lg * 4 + i;
        float val = acc[n][i] + bl[n];
        if (mat == 0){
          Qs[r * ND + f] = f2bf(val * QK_SCALE);
        } else if (mat == 1){
          Ks[r * ND + (f ^ ((r & 7) << 3))] = f2bf(val);
        } else {
          int bb = r >> 12, nt = r & (NT - 1);
          VTs[(bb * ND + f) * NT + (nt ^ ((f & 3) << 3) ^ (((f >> 2) & 1) << 2))] = f2bf(val);
        }
      }
    }
  }
}

// ---------------- kernel 2: flash attention, 16x16 MFMA, no P round-trip ----------
// grid 256 = 4 batches x 64 q-blocks(64 q). 8 waves = 2 q-waves(32 q) x 4 kv-groups.
// S^T = mfma16(K, Q): lane holds P[kv = n*16+lg*4+i][q=lm].
// PV A-frag = cvt_pk of st regs with slot map (lg,j)->kv: j0-3 = lg*4+j, j4-7 = 16+lg*4+j-4.
// PV B-frag = 2x ds_read_b64 at matching kv bases. Same bijection both sides -> correct
// for ANY hardware k-map (A/B symmetry verified by R2/R6/R7 passes).
__global__ __launch_bounds__(512, 2) void k_attn(
    const u16* __restrict__ Qs, const u16* __restrict__ Ks,
    const u16* __restrict__ VTs, float* __restrict__ Out)
{
  __shared__ __align__(16) u16 lds[65536];          // 128 KiB
  u16* kbuf = lds;                                  // [2][4][32*128]
  u16* vbuf = lds + 32768;                          // [2][4][128*32]

  // XCD-chunked: xcd = lin&7 -> batch b = xcd>>1; 2 XCDs per batch (K/V fit in L2)
  const int lin = blockIdx.x;
  const int b   = (lin & 7) >> 1;
  const int qb  = (lin >> 3) + ((lin & 1) << 5);    // 0..63

  const int lane = threadIdx.x & 63;
  const int w  = threadIdx.x >> 6;
  const int g  = w >> 1, qw = w & 1;                // kv-group, q-wave
  const int lm = lane & 15, lg = lane >> 4;
  const int q0 = b * NT + qb * 64 + qw * 32;        // global q base for this wave

  // Q frags in registers: rows q0 + sq*16 + lm, k = kc*32 + lg*8 + j  (R2 map)
  s16x8 aq[2][4];
  #pragma unroll
  for (int sq = 0; sq < 2; ++sq){
    const u16* qr = Qs + (size_t)(q0 + sq * 16 + lm) * ND;
    #pragma unroll
    for (int kc = 0; kc < 4; ++kc) aq[sq][kc] = *(const s16x8*)(qr + kc * 32 + lg * 8);
  }

  f32x4 o[2][8];
  #pragma unroll
  for (int sq = 0; sq < 2; ++sq)
    #pragma unroll
    for (int n = 0; n < 8; ++n) o[sq][n] = f32x4{0.f,0.f,0.f,0.f};
  float l_[2] = {0.f, 0.f};

  // staging pointers (group g covers kv [g*1024, g*1024+1024), tiles of 32)
  const u16* gk = Ks  + ((size_t)b * NT + g * 1024 + qw * 16 + (lane >> 4)) * ND + (lane & 15) * 8;
  const u16* gv = VTs + ((size_t)b * ND + qw * 64 + (lane >> 2)) * NT + g * 1024 + (lane & 3) * 8;

  auto stage = [&](int par){
    u16* kd = kbuf + par * 16384 + g * 4096 + qw * 2048;
    u16* vd = vbuf + par * 16384 + g * 4096 + qw * 2048;
    #pragma unroll
    for (int j = 0; j < 4; ++j){
      __builtin_amdgcn_global_load_lds((const as1_void*)(gk + (size_t)j * 4 * ND),
                                       (as3_void*)(kd + j * 512), 16, 0, 0);
      __builtin_amdgcn_global_load_lds((const as1_void*)(gv + (size_t)j * 16 * NT),
                                       (as3_void*)(vd + j * 512), 16, 0, 0);
    }
    gk += (size_t)32 * ND;
    gv += 32;
  };

  stage(0);
  __syncthreads();
  int par = 0;

  const int kswz = (lm & 7) << 3;                           // K b128-read swizzle
  const int vswz = ((lm & 3) << 3) ^ (((lm >> 2) & 1) << 2);// V b64-read swizzle
  const int vcol0 = (lg * 4) ^ vswz;                        // kv lg*4 + {0..3}
  const int vcol1 = (16 + lg * 4) ^ vswz;                   // kv 16+lg*4 + {0..3}

  for (int t = 0; t < 32; ++t){
    if (t < 31) stage(par ^ 1);                 // prefetch next tile
    const u16* kb = kbuf + par * 16384 + g * 4096;
    const u16* vb = vbuf + par * 16384 + g * 4096;

    // ---- S^T = K Q : swapped operands; kf shared across sq ----
    f32x4 st[2][2];
    #pragma unroll
    for (int sq = 0; sq < 2; ++sq)
      #pragma unroll
      for (int n = 0; n < 2; ++n) st[sq][n] = f32x4{0.f,0.f,0.f,0.f};
    __builtin_amdgcn_s_setprio(1);
    #pragma unroll
    for (int kc = 0; kc < 4; ++kc){
      #pragma unroll
      for (int n = 0; n < 2; ++n){
        s16x8 kf = *(const s16x8*)&kb[(n * 16 + lm) * 128 + ((kc * 32 + lg * 8) ^ kswz)];
        st[0][n] = mfma16(kf, aq[0][kc], st[0][n]);
        st[1][n] = mfma16(kf, aq[1][kc], st[1][n]);
      }
    }
    __builtin_amdgcn_s_setprio(0);

    // ---- fixed-ref softmax in registers; pack PV A-frags (no LDS) ----
    s16x8 pa[2];
    #pragma unroll
    for (int sq = 0; sq < 2; ++sq){
      float p[8];
      #pragma unroll
      for (int n = 0; n < 2; ++n)
        #pragma unroll
        for (int i = 0; i < 4; ++i){
          p[n * 4 + i] = __builtin_amdgcn_exp2f(st[sq][n][i]);
          l_[sq] += p[n * 4 + i];
        }
      pa[sq] = __builtin_bit_cast(s16x8, u32x4{
          cvtpk(p[0], p[1]), cvtpk(p[2], p[3]),
          cvtpk(p[4], p[5]), cvtpk(p[6], p[7])});
    }

    // ---- O += P V : vf = 2x b64 at kv bases lg*4 / 16+lg*4; shared across sq ----
    __builtin_amdgcn_s_setprio(1);
    #pragma unroll
    for (int nf = 0; nf < 8; ++nf){
      const int vr = (nf * 16 + lm) * 32;
      u32x2 v0 = *(const u32x2*)&vb[vr + vcol0];
      u32x2 v1 = *(const u32x2*)&vb[vr + vcol1];
      s16x8 vf = __builtin_bit_cast(s16x8, u32x4{v0[0], v0[1], v1[0], v1[1]});
      o[0][nf] = mfma16(pa[0], vf, o[0][nf]);
      o[1][nf] = mfma16(pa[1], vf, o[1][nf]);
    }
    __builtin_amdgcn_s_setprio(0);

    __syncthreads();   // drains prefetch vmcnt + releases buf[par]
    par ^= 1;
  }

  // ---- epilogue: reduce l over lg; merge 4 kv-groups in LDS; write Out ----
  #pragma unroll
  for (int sq = 0; sq < 2; ++sq){
    float v = l_[sq];
    v += __shfl_xor(v, 16);
    v += __shfl_xor(v, 32);
    l_[sq] = v;                       // all lanes: l for q = sq*16+lm
  }

  float* mbF = (float*)lds;            // [3][64][128] f32 partial O (96 KiB)
  float* lF  = (float*)lds + 24576;    // [4][64] f32 partial l (1 KiB)
  __syncthreads();                     // everyone past the K/V buffers
  if (lg == 0){
    lF[g * 64 + qw * 32 + lm]      = l_[0];
    lF[g * 64 + qw * 32 + 16 + lm] = l_[1];
  }
  if (g){
    #pragma unroll
    for (int sq = 0; sq < 2; ++sq){
      #pragma unroll
      for (int i = 0; i < 4; ++i){
        const int row = (g - 1) * 64 + qw * 32 + sq * 16 + lg * 4 + i;
        #pragma unroll
        for (int nf = 0; nf < 8; ++nf)
          mbF[row * 128 + nf * 16 + lm] = o[sq][nf][i];
      }
    }
  }
  __syncthreads();
  if (!g){
    #pragma unroll
    for (int sq = 0; sq < 2; ++sq){
      #pragma unroll
      for (int i = 0; i < 4; ++i){
        const int rloc = qw * 32 + sq * 16 + lg * 4 + i;
        const float inv = 1.f / (lF[rloc] + lF[64 + rloc] + lF[128 + rloc] + lF[192 + rloc]);
        const size_t r = (size_t)(q0 + sq * 16 + lg * 4 + i);
        #pragma unroll
        for (int nf = 0; nf < 8; ++nf){
          const int f = nf * 16 + lm;
          float val = o[sq][nf][i] + mbF[rloc * 128 + f]
                    + mbF[(64 + rloc) * 128 + f] + mbF[(128 + rloc) * 128 + f];
          Out[r * ND + f] = val * inv;
        }
      }
    }
  }
}

extern "C" void kernel_launch(void* const* d_in, const int* in_sizes, int n_in,
                              void* d_out, int out_size, void* d_ws, size_t ws_size,
                              hipStream_t stream) {
  const float* X  = (const float*)d_in[0];
  const float* Wq = (const float*)d_in[1];
  const float* bq = (const float*)d_in[2];
  const float* Wk = (const float*)d_in[3];
  const float* bk = (const float*)d_in[4];
  const float* Wv = (const float*)d_in[5];
  const float* bv = (const float*)d_in[6];
  float* Out = (float*)d_out;

  u16* Qs  = (u16*)d_ws;                        // 4 MiB
  u16* Ks  = Qs  + (size_t)NQ * ND;             // 4 MiB
  u16* VTs = Ks  + (size_t)NQ * ND;             // 4 MiB
  u16* WT  = VTs + (size_t)NQ * ND;             // 96 KiB

  hipLaunchKernelGGL(k_wprep, dim3(3 * 128), dim3(128), 0, stream, Wq, Wk, Wv, WT);
  hipLaunchKernelGGL(k_proj,  dim3(NQ / 64), dim3(256), 0, stream,
                     X, WT, bq, bk, bv, Qs, Ks, VTs);
  hipLaunchKernelGGL(k_attn,  dim3(256), dim3(512), 0, stream, Qs, Ks, VTs, Out);
}